// Round 8
// baseline (46.984 us; speedup 1.0000x reference)
//
#include <hip/hip_runtime.h>
#include <cstdint>
#include <cstddef>

// Problem constants
#define B_ 256
#define D_ 512
#define P_ 128
#define E_ 128

typedef unsigned short u16;
typedef unsigned int   u32;
typedef __bf16  bf16x8_t __attribute__((ext_vector_type(8)));
typedef float   f32x4_t  __attribute__((ext_vector_type(4)));
typedef u16     u16x4_t  __attribute__((ext_vector_type(4)));
typedef u16     u16x8_t  __attribute__((ext_vector_type(8)));

__device__ __forceinline__ u16 f2bf(float f) {
  union { float f; unsigned int u; } c; c.f = f;
  unsigned int u = c.u;
  unsigned int r = (u + 0x7FFFu + ((u >> 16) & 1u)) >> 16;
  return (u16)r;
}
__device__ __forceinline__ u32 pk2bf(float a, float b) {
  return (u32)f2bf(a) | ((u32)f2bf(b) << 16);
}
__device__ __forceinline__ float bf2f(u16 v) {
  union { unsigned int u; float f; } c; c.u = (unsigned int)v << 16;
  return c.f;
}

// ---------------------------------------------------------------------------
// Pass 1: transpose + convert x f32 -> bf16 (verified).
// src [b][512 d][128 p] f32 -> xT[p][b][d] bf16.
// ---------------------------------------------------------------------------
__global__ __launch_bounds__(256) void transpose_cvt_kernel(
    const float* __restrict__ src, u16* __restrict__ dst) {
  __shared__ float tile[64][65];

  const int o  = blockIdx.x;          // b
  const int r0 = blockIdx.y * 64;     // d block
  const int c0 = blockIdx.z * 64;     // p block
  const int t  = threadIdx.x;

  const float* s = src + (size_t)o * D_ * 128 + (size_t)r0 * 128 + c0;

  {
    const int lr = t >> 4;
    const int lc = (t & 15) * 4;
    #pragma unroll
    for (int it = 0; it < 4; ++it) {
      const int r = lr + it * 16;
      const float4 v = *reinterpret_cast<const float4*>(s + (size_t)r * 128 + lc);
      tile[r][lc + 0] = v.x; tile[r][lc + 1] = v.y;
      tile[r][lc + 2] = v.z; tile[r][lc + 3] = v.w;
    }
  }
  __syncthreads();

  {
    const int wc = t >> 3;
    const int wd = (t & 7) * 8;
    #pragma unroll
    for (int it = 0; it < 2; ++it) {
      const int c = wc + it * 32;
      u16x8_t pkv;
      #pragma unroll
      for (int j = 0; j < 8; ++j) pkv[j] = f2bf(tile[wd + j][c]);
      *reinterpret_cast<u16x8_t*>(dst + (size_t)(c0 + c) * (B_ * D_) +
                                  (size_t)o * D_ + r0 + wd) = pkv;
    }
  }
}

// ---------------------------------------------------------------------------
// Pass 2: per-p bf16 TN GEMM, 64x64xBK64, 4 waves, depth-2 counted-vmcnt.
//   A = xT[p][b][d] bf16 via global_load_lds (pre-swizzled source)
//   B = W[p][d][e] f32 reg-staged -> cvt bf16 -> swizzled ds_write (r4-style,
//       exonerated: the r3/r4 47us floor was the store scatter, not this)
//   epilogue: COALESCED bf16 store to ws2[p][b][e] (+bias)
// Grid = 128p x 4bt x 2et = 1024 WGs = 4 WG/CU, XCD-swizzled p.
// ---------------------------------------------------------------------------

// swizzled elem index of 16B chunk g (0..7) in row `row` of a [64]x[64]-u16 tile
#define SWZ_ELEM(row, g) (((row) << 6) + ((((g) ^ ((row) & 7))) << 3))
// swizzled u32 index for k-pair kk (0..31) in row er (same tile, same XOR)
#define SWZ_BU32(er, kk) (((er) << 5) + ((((kk) >> 2) ^ ((er) & 7)) << 2) + ((kk) & 3))

struct BReg { float4 a0, a1, b0, b1; };

__global__ __launch_bounds__(256, 4) void gemm_kernel(
    const u16* __restrict__ xT, const float* __restrict__ W,
    const float* __restrict__ bias, u16* __restrict__ ws2) {
  __shared__ __attribute__((aligned(16))) u16 As[2][64 * 64];
  __shared__ __attribute__((aligned(16))) u16 Bs[2][64 * 64];

  const int wg   = blockIdx.x;
  const int xcd  = wg & 7;
  const int i    = wg >> 3;            // 0..127
  const int p    = xcd * 16 + (i & 15);
  const int tile = i >> 4;             // 0..7
  const int b0   = (tile & 3) * 64;
  const int e0t  = (tile >> 2) * 64;

  const int t    = threadIdx.x;
  const int lane = t & 63;
  const int wv   = t >> 6;
  const int wr   = wv >> 1;            // wave row (b half)
  const int wc   = wv & 1;             // wave col (e half)

  const u16*   Ag = xT + (size_t)p * (B_ * D_) + (size_t)b0 * D_;
  const float* Wg = W + (size_t)p * (D_ * E_) + e0t;

  // A staging: chunks t, t+256; LDS dest linear, global source pre-swizzled.
  const int r1 = t >> 3;
  const int sw = (((t & 7) ^ (r1 & 7)) << 3);
  // B staging: d-pair k2 (d = 2k2, 2k2+1), e-quad eq (e = 4eq, +32)
  const int k2 = t & 31;
  const int eq = t >> 5;

  const int fr = lane & 15;
  const int fq = lane >> 4;

  f32x4_t acc[2][2] = {};
  BReg rB0, rB1;

#define STAGE_A(buf, d0) do { \
    __builtin_amdgcn_global_load_lds( \
        (const __attribute__((address_space(1))) void*)(Ag + (size_t)r1 * D_ + (d0) + sw), \
        (__attribute__((address_space(3))) void*)&As[buf][wv * 512], 16, 0, 0); \
    __builtin_amdgcn_global_load_lds( \
        (const __attribute__((address_space(1))) void*)(Ag + (size_t)(r1 + 32) * D_ + (d0) + sw), \
        (__attribute__((address_space(3))) void*)&As[buf][2048 + wv * 512], 16, 0, 0); \
  } while (0)

#define LOAD_B(d0, RB) do { \
    const float* wp = Wg + (size_t)((d0) + 2 * k2) * E_ + 4 * eq; \
    RB.a0 = *reinterpret_cast<const float4*>(wp); \
    RB.a1 = *reinterpret_cast<const float4*>(wp + E_); \
    RB.b0 = *reinterpret_cast<const float4*>(wp + 32); \
    RB.b1 = *reinterpret_cast<const float4*>(wp + E_ + 32); \
  } while (0)

#define WRITE_B(buf, RB) do { \
    u32* bs = reinterpret_cast<u32*>(&Bs[buf][0]); \
    const int e = 4 * eq; \
    bs[SWZ_BU32(e + 0, k2)]  = pk2bf(RB.a0.x, RB.a1.x); \
    bs[SWZ_BU32(e + 1, k2)]  = pk2bf(RB.a0.y, RB.a1.y); \
    bs[SWZ_BU32(e + 2, k2)]  = pk2bf(RB.a0.z, RB.a1.z); \
    bs[SWZ_BU32(e + 3, k2)]  = pk2bf(RB.a0.w, RB.a1.w); \
    bs[SWZ_BU32(e + 32, k2)] = pk2bf(RB.b0.x, RB.b1.x); \
    bs[SWZ_BU32(e + 33, k2)] = pk2bf(RB.b0.y, RB.b1.y); \
    bs[SWZ_BU32(e + 34, k2)] = pk2bf(RB.b0.z, RB.b1.z); \
    bs[SWZ_BU32(e + 35, k2)] = pk2bf(RB.b0.w, RB.b1.w); \
  } while (0)

#define MFMA(a, b, c) __builtin_amdgcn_mfma_f32_16x16x32_bf16((a), (b), (c), 0, 0, 0)

  // per tile: 4 LOAD_B + 2 STAGE_A = 6 vm-ops. Depth-2: at the wait point
  // 12 outstanding; vmcnt(6) completes exactly tile k+1 (A in LDS, B in regs).
#define K_ITER(KT, RBW, RBL, PREFETCH, VMSTR, TAIL) do { \
    const int rowa = wr * 32 + fr, rowb = wc * 32 + fr; \
    bf16x8_t af0 = *reinterpret_cast<const bf16x8_t*>(&As[(KT) & 1][SWZ_ELEM(rowa, fq)]); \
    bf16x8_t af1 = *reinterpret_cast<const bf16x8_t*>(&As[(KT) & 1][SWZ_ELEM(rowa, 4 + fq)]); \
    bf16x8_t af2 = *reinterpret_cast<const bf16x8_t*>(&As[(KT) & 1][SWZ_ELEM(rowa + 16, fq)]); \
    bf16x8_t af3 = *reinterpret_cast<const bf16x8_t*>(&As[(KT) & 1][SWZ_ELEM(rowa + 16, 4 + fq)]); \
    bf16x8_t bf0 = *reinterpret_cast<const bf16x8_t*>(&Bs[(KT) & 1][SWZ_ELEM(rowb, fq)]); \
    bf16x8_t bf1 = *reinterpret_cast<const bf16x8_t*>(&Bs[(KT) & 1][SWZ_ELEM(rowb, 4 + fq)]); \
    bf16x8_t bf2 = *reinterpret_cast<const bf16x8_t*>(&Bs[(KT) & 1][SWZ_ELEM(rowb + 16, fq)]); \
    bf16x8_t bf3 = *reinterpret_cast<const bf16x8_t*>(&Bs[(KT) & 1][SWZ_ELEM(rowb + 16, 4 + fq)]); \
    asm volatile("s_waitcnt lgkmcnt(0)" ::: "memory"); \
    __builtin_amdgcn_sched_barrier(0); \
    __builtin_amdgcn_s_barrier(); \
    if (PREFETCH) { LOAD_B(((KT) + 2) * 64, RBL); STAGE_A((KT) & 1, ((KT) + 2) * 64); } \
    acc[0][0] = MFMA(af0, bf0, acc[0][0]); \
    acc[0][1] = MFMA(af0, bf2, acc[0][1]); \
    acc[1][0] = MFMA(af2, bf0, acc[1][0]); \
    acc[1][1] = MFMA(af2, bf2, acc[1][1]); \
    acc[0][0] = MFMA(af1, bf1, acc[0][0]); \
    acc[0][1] = MFMA(af1, bf3, acc[0][1]); \
    acc[1][0] = MFMA(af3, bf1, acc[1][0]); \
    acc[1][1] = MFMA(af3, bf3, acc[1][1]); \
    if (!(TAIL)) { \
      asm volatile("s_waitcnt " VMSTR ::: "memory"); \
      __builtin_amdgcn_sched_barrier(0); \
      WRITE_B(((KT) + 1) & 1, RBW); \
      asm volatile("s_waitcnt lgkmcnt(0)" ::: "memory"); \
      __builtin_amdgcn_s_barrier(); \
    } \
  } while (0)

  // ---- prologue: tiles 0 and 1 in flight; finish tile 0; barrier ----
  LOAD_B(0, rB0);
  STAGE_A(0, 0);
  asm volatile("" ::: "memory");
  __builtin_amdgcn_sched_barrier(0);   // tile0 ops strictly before tile1 ops
  LOAD_B(64, rB1);
  STAGE_A(1, 64);
  asm volatile("s_waitcnt vmcnt(6)" ::: "memory");
  __builtin_amdgcn_sched_barrier(0);
  WRITE_B(0, rB0);
  asm volatile("s_waitcnt lgkmcnt(0)" ::: "memory");
  __builtin_amdgcn_s_barrier();

  K_ITER(0, rB1, rB0, 1, "vmcnt(6)", 0);
  K_ITER(1, rB0, rB1, 1, "vmcnt(6)", 0);
  K_ITER(2, rB1, rB0, 1, "vmcnt(6)", 0);
  K_ITER(3, rB0, rB1, 1, "vmcnt(6)", 0);
  K_ITER(4, rB1, rB0, 1, "vmcnt(6)", 0);
  K_ITER(5, rB0, rB1, 1, "vmcnt(6)", 0);
  K_ITER(6, rB1, rB0, 0, "vmcnt(0)", 0);
  K_ITER(7, rB0, rB1, 0, "vmcnt(0)", 1);

#undef K_ITER
#undef MFMA
#undef STAGE_A
#undef LOAD_B
#undef WRITE_B

  // ---- epilogue: coalesced bf16 store to ws2[p][b][e] (+bias) ----
  const int q4 = fq * 4;
  #pragma unroll
  for (int jj = 0; jj < 2; ++jj) {
    const int e  = e0t + wc * 32 + jj * 16 + fr;
    const float bv = bias[p * E_ + e];
    #pragma unroll
    for (int ii = 0; ii < 2; ++ii) {
      const int r0 = b0 + wr * 32 + ii * 16 + q4;
      #pragma unroll
      for (int rg = 0; rg < 4; ++rg) {
        ws2[((size_t)p * B_ + (r0 + rg)) * E_ + e] = f2bf(acc[ii][jj][rg] + bv);
      }
    }
  }
}

// ---------------------------------------------------------------------------
// Pass 3: ws2[p][b][e] bf16 -> out[b][e][p] f32; padded-LDS 64x64 transpose,
// coalesced read (e-contiguous bf16) and write (p-contiguous float4).
// Grid: (b=256, pblk=2, eblk=2).
// ---------------------------------------------------------------------------
__global__ __launch_bounds__(256) void out_transpose_kernel(
    const u16* __restrict__ ws2, float* __restrict__ out) {
  __shared__ float tile[64][65];

  const int b  = blockIdx.x;
  const int p0 = blockIdx.y * 64;
  const int e0 = blockIdx.z * 64;
  const int t  = threadIdx.x;

  const u16* s = ws2 + ((size_t)p0 * B_ + b) * E_ + e0;   // p-row stride B_*E_

  {
    const int lr = t >> 4;          // p-local row 0..15
    const int lc = (t & 15) * 4;    // e-local col
    #pragma unroll
    for (int it = 0; it < 4; ++it) {
      const int r = lr + it * 16;
      const u16x4_t v = *reinterpret_cast<const u16x4_t*>(s + (size_t)r * (B_ * E_) + lc);
      tile[r][lc + 0] = bf2f(v[0]); tile[r][lc + 1] = bf2f(v[1]);
      tile[r][lc + 2] = bf2f(v[2]); tile[r][lc + 3] = bf2f(v[3]);
    }
  }
  __syncthreads();

  {
    const int c  = t >> 4;          // e-local col base
    const int wd = (t & 15) * 4;    // p-local row chunk
    #pragma unroll
    for (int it = 0; it < 4; ++it) {
      const int cc = c + it * 16;
      float4 v;
      v.x = tile[wd + 0][cc]; v.y = tile[wd + 1][cc];
      v.z = tile[wd + 2][cc]; v.w = tile[wd + 3][cc];
      *reinterpret_cast<float4*>(out + ((size_t)b * E_ + e0 + cc) * P_ + p0 + wd) = v;
    }
  }
}

// ---------------------------------------------------------------------------
// Fallback (only if workspace is too small): naive but correct.
// ---------------------------------------------------------------------------
__global__ __launch_bounds__(256) void naive_kernel(
    const float* __restrict__ x, const float* __restrict__ W,
    const float* __restrict__ bias, float* __restrict__ out) {
  const size_t idx = (size_t)blockIdx.x * 256 + threadIdx.x;
  const int p = (int)(idx & 127);
  const int e = (int)((idx >> 7) & 127);
  const int b = (int)(idx >> 14);
  float acc = bias[p * E_ + e];
  const float* xp = x + (size_t)b * D_ * P_ + p;
  const float* wp = W + (size_t)p * D_ * E_ + e;
  for (int d = 0; d < D_; ++d) acc += xp[(size_t)d * P_] * wp[(size_t)d * E_];
  out[idx] = acc;
}

extern "C" void kernel_launch(void* const* d_in, const int* in_sizes, int n_in,
                              void* d_out, int out_size, void* d_ws, size_t ws_size,
                              hipStream_t stream) {
  (void)in_sizes; (void)n_in; (void)out_size;
  const float* x    = (const float*)d_in[0];   // [B,D,P] f32
  const float* W    = (const float*)d_in[1];   // [P,D,E] f32
  const float* bias = (const float*)d_in[2];   // [P,E]   f32
  float* out = (float*)d_out;                  // [B,E,P] f32

  const size_t xT_bytes  = (size_t)P_ * B_ * D_ * 2;   // 32 MiB
  const size_t ws2_bytes = (size_t)P_ * B_ * E_ * 2;   // 8 MiB

  if (ws_size < xT_bytes + ws2_bytes) {
    naive_kernel<<<dim3((B_ * E_ * P_) / 256), 256, 0, stream>>>(x, W, bias, out);
    return;
  }

  u16* xT  = (u16*)d_ws;                               // [P][B][D] bf16
  u16* ws2 = (u16*)((char*)d_ws + xT_bytes);           // [P][B][E] bf16

  transpose_cvt_kernel<<<dim3(B_, 8, 2), 256, 0, stream>>>(x, xT);
  gemm_kernel<<<dim3(1024), 256, 0, stream>>>(xT, W, bias, ws2);
  out_transpose_kernel<<<dim3(B_, 2, 2), 256, 0, stream>>>(ws2, out);
}